// Round 13
// baseline (38.448 us; speedup 1.0000x reference)
//
#include <hip/hip_runtime.h>

#define NBINS 128
#define NFREQ 64
#define HDIM 128
#define NQ 16384
#define EPSF 1e-8f

typedef _Float16 h2 __attribute__((ext_vector_type(2)));
#define B2(x) __builtin_bit_cast(h2, (x))
#define U32(x) __builtin_bit_cast(unsigned, (x))

__device__ __forceinline__ h2 cvt_pk(float a, float b) {
  return __builtin_bit_cast(h2, __builtin_amdgcn_cvt_pkrtz(a, b));
}

// d_ws layout (dwords):
//   [0, 8192)      EP[c][b][fj]: (pr,pi) h2 word; c=8-freq chunk, b=bin, fj=0..7
//   [8192, 12288)  WP[c][b][fp]: (-softplus(w)) h2 pairs
//   [12288, 16384) MP[c][b][fp]: (mw) h2 pairs
//   [16384, ...)   Qb: per (group g=q>>2, fq quarter) segment of 96 dwords at
//                  (g*4+fq)*96: [qq 0..3][ eq[16] | qmw[8] ]  (f16 pairs)
//                  eq word j = (-qr,-qi) for freq fq*16+j; qmw p = (qm,qm) pair.
#define QB_WOFF 16384
#define WS_NEEDED (((size_t)QB_WOFF + (size_t)NQ * 24) * 4)   // ~6.4 MB

#define QN_BLOCKS 256
#define PACK_BLOCKS 4

// ---------- fused prologue: Qb build (blocks 0..255) + probe pack (256..259) ----------
__global__ __launch_bounds__(256) void prologue13(
    const float* __restrict__ Q,
    const float* __restrict__ probes,
    const float* __restrict__ wraw,
    const float* __restrict__ mw,
    unsigned* __restrict__ ws) {
  const int blk = blockIdx.x;
  const int t = threadIdx.x;
  if (blk < QN_BLOCKS) {
    const int l = t & 3;                 // lane-of-query: owns freqs [16l, 16l+16)
    const int q = blk * 64 + (t >> 2);
    const float* qp = Q + (size_t)q * HDIM;
    float re[16], im[16];
    #pragma unroll
    for (int k = 0; k < 4; ++k) {
      *reinterpret_cast<float4*>(&re[k * 4]) =
          *reinterpret_cast<const float4*>(qp + 16 * l + k * 4);
      *reinterpret_cast<float4*>(&im[k * 4]) =
          *reinterpret_cast<const float4*>(qp + NFREQ + 16 * l + k * 4);
    }
    float s = 0.0f;
    #pragma unroll
    for (int k = 0; k < 16; ++k) {
      s = fmaf(re[k], re[k], s);
      s = fmaf(im[k], im[k], s);
    }
    s += __shfl_xor(s, 1, 4);
    s += __shfl_xor(s, 2, 4);
    const float inv = 1.0f / (__builtin_amdgcn_sqrtf(s) + EPSF);
    unsigned eq[16], qmw[8];
    float qm[16];
    #pragma unroll
    for (int k = 0; k < 16; ++k) {
      const float qr = re[k] * inv;
      const float qi = im[k] * inv;
      h2 v = {(_Float16)(-qr), (_Float16)(-qi)};
      eq[k] = U32(v);
      qm[k] = __builtin_amdgcn_sqrtf(fmaf(qr, qr, fmaf(qi, qi, EPSF)));
    }
    #pragma unroll
    for (int p = 0; p < 8; ++p) {
      h2 v = {(_Float16)qm[2 * p], (_Float16)qm[2 * p + 1]};
      qmw[p] = U32(v);
    }
    unsigned* seg = ws + QB_WOFF + ((size_t)(q >> 2) * 4 + l) * 96 + (q & 3) * 24;
    *reinterpret_cast<uint4*>(seg + 0)  = make_uint4(eq[0], eq[1], eq[2], eq[3]);
    *reinterpret_cast<uint4*>(seg + 4)  = make_uint4(eq[4], eq[5], eq[6], eq[7]);
    *reinterpret_cast<uint4*>(seg + 8)  = make_uint4(eq[8], eq[9], eq[10], eq[11]);
    *reinterpret_cast<uint4*>(seg + 12) = make_uint4(eq[12], eq[13], eq[14], eq[15]);
    *reinterpret_cast<uint4*>(seg + 16) = make_uint4(qmw[0], qmw[1], qmw[2], qmw[3]);
    *reinterpret_cast<uint4*>(seg + 20) = make_uint4(qmw[4], qmw[5], qmw[6], qmw[7]);
  } else {
    const int id = (blk - QN_BLOCKS) * 256 + t;  // 1024 ids: (c,b)
    if (id >= 1024) return;
    const int c = id >> 7, b = id & 127;
    const float* pb = probes + b * HDIM + c * 8;
    const float* wb = wraw + b * NFREQ + c * 8;
    const float* mb = mw + b * NFREQ + c * 8;
    float pr[8], pi[8], w[8], m[8];
    *reinterpret_cast<float4*>(&pr[0]) = *reinterpret_cast<const float4*>(pb);
    *reinterpret_cast<float4*>(&pr[4]) = *reinterpret_cast<const float4*>(pb + 4);
    *reinterpret_cast<float4*>(&pi[0]) = *reinterpret_cast<const float4*>(pb + NFREQ);
    *reinterpret_cast<float4*>(&pi[4]) = *reinterpret_cast<const float4*>(pb + NFREQ + 4);
    *reinterpret_cast<float4*>(&w[0])  = *reinterpret_cast<const float4*>(wb);
    *reinterpret_cast<float4*>(&w[4])  = *reinterpret_cast<const float4*>(wb + 4);
    *reinterpret_cast<float4*>(&m[0])  = *reinterpret_cast<const float4*>(mb);
    *reinterpret_cast<float4*>(&m[4])  = *reinterpret_cast<const float4*>(mb + 4);
    unsigned ep[8], wp[4], mp[4];
    #pragma unroll
    for (int j = 0; j < 8; ++j) {
      h2 v = {(_Float16)pr[j], (_Float16)pi[j]};
      ep[j] = U32(v);
    }
    #pragma unroll
    for (int k = 0; k < 4; ++k) {
      float w0 = w[2 * k], w1 = w[2 * k + 1];
      float n0 = -(fmaxf(w0, 0.0f) + log1pf(expf(-fabsf(w0))));  // -softplus
      float n1 = -(fmaxf(w1, 0.0f) + log1pf(expf(-fabsf(w1))));
      h2 vw = {(_Float16)n0, (_Float16)n1};
      h2 vm = {(_Float16)m[2 * k], (_Float16)m[2 * k + 1]};
      wp[k] = U32(vw);
      mp[k] = U32(vm);
    }
    unsigned* EP = ws + (size_t)(c * 128 + b) * 8;
    *reinterpret_cast<uint4*>(EP)     = make_uint4(ep[0], ep[1], ep[2], ep[3]);
    *reinterpret_cast<uint4*>(EP + 4) = make_uint4(ep[4], ep[5], ep[6], ep[7]);
    unsigned* WP = ws + 8192 + (size_t)(c * 128 + b) * 4;
    *reinterpret_cast<uint4*>(WP) = make_uint4(wp[0], wp[1], wp[2], wp[3]);
    unsigned* MP = ws + 12288 + (size_t)(c * 128 + b) * 4;
    *reinterpret_cast<uint4*>(MP) = make_uint4(mp[0], mp[1], mp[2], mp[3]);
  }
}

// ---------- scorer13: q-data in SGPRs (one up-front s_load batch); no LDS in loop ----
// Block = 256 thr = 4 waves = fq quarters 0..3 over the SAME 4 queries (g = blockIdx).
// Wave: 4q x 128 bins (lane=bin, 2 copies) x 16 freqs. Probe VMEM per-lane as r12.
__global__ __launch_bounds__(256, 8) void scorer13(
    const unsigned* __restrict__ ws,
    const float* __restrict__ bias,
    float* __restrict__ out) {
  __shared__ float part[3][4][2][64];   // 6 KB: fq 1..3 partials
  const int t = threadIdx.x;
  const int lane = t & 63;
  const int fq = __builtin_amdgcn_readfirstlane(t >> 6);
  const int g = blockIdx.x;             // query group of 4

  // Wave-uniform q-data pointer -> compiler emits s_load; 96 dwords per wave.
  const unsigned* qd = ws + QB_WOFF + ((size_t)g * 4 + fq) * 96;

  float acc[4][2];
  #pragma unroll
  for (int q = 0; q < 4; ++q) acc[q][0] = acc[q][1] = 0.0f;

  #pragma unroll 1
  for (int ci = 0; ci < 2; ++ci) {
    const int c = fq * 2 + ci;          // global 8-freq chunk
    // per-lane probe words for this chunk, both bin-copies (32 dwords)
    const unsigned* EPb = ws + (size_t)(c * 128 + lane) * 8;
    const unsigned* WPb = ws + 8192 + (size_t)(c * 128 + lane) * 4;
    const unsigned* MPb = ws + 12288 + (size_t)(c * 128 + lane) * 4;
    const uint4 e0a = *reinterpret_cast<const uint4*>(EPb);
    const uint4 e0b = *reinterpret_cast<const uint4*>(EPb + 4);
    const uint4 e1a = *reinterpret_cast<const uint4*>(EPb + 512);
    const uint4 e1b = *reinterpret_cast<const uint4*>(EPb + 516);
    const uint4 w0v = *reinterpret_cast<const uint4*>(WPb);
    const uint4 w1v = *reinterpret_cast<const uint4*>(WPb + 256);
    const uint4 m0v = *reinterpret_cast<const uint4*>(MPb);
    const uint4 m1v = *reinterpret_cast<const uint4*>(MPb + 256);
    const unsigned ep[2][8] = {
        {e0a.x, e0a.y, e0a.z, e0a.w, e0b.x, e0b.y, e0b.z, e0b.w},
        {e1a.x, e1a.y, e1a.z, e1a.w, e1b.x, e1b.y, e1b.z, e1b.w}};
    const unsigned wp[2][4] = {{w0v.x, w0v.y, w0v.z, w0v.w},
                               {w1v.x, w1v.y, w1v.z, w1v.w}};
    const unsigned mp[2][4] = {{m0v.x, m0v.y, m0v.z, m0v.w},
                               {m1v.x, m1v.y, m1v.z, m1v.w}};
    #pragma unroll
    for (int q = 0; q < 4; ++q) {
      #pragma unroll
      for (int half = 0; half < 2; ++half) {
        // SGPR q-operands: constant offsets into the wave-uniform segment
        const unsigned qe0 = qd[q * 24 + ci * 8 + half * 4 + 0];
        const unsigned qe1 = qd[q * 24 + ci * 8 + half * 4 + 1];
        const unsigned qe2 = qd[q * 24 + ci * 8 + half * 4 + 2];
        const unsigned qe3 = qd[q * 24 + ci * 8 + half * 4 + 3];
        const unsigned qm0 = qd[q * 24 + 16 + ci * 4 + half * 2 + 0];
        const unsigned qm1 = qd[q * 24 + 16 + ci * 4 + half * 2 + 1];
        #pragma unroll
        for (int bc = 0; bc < 2; ++bc) {
          float da = acc[q][bc];
          {
            const int wi = half * 4;
            h2 e0 = B2(ep[bc][wi])     + B2(qe0);   // v_pk_add_f16, 1 SGPR src
            h2 e1 = B2(ep[bc][wi + 1]) + B2(qe1);
            float d0 = __builtin_amdgcn_fdot2(e0, e0, EPSF, false);
            float d1 = __builtin_amdgcn_fdot2(e1, e1, EPSF, false);
            h2 dp = cvt_pk(__builtin_amdgcn_sqrtf(d0), __builtin_amdgcn_sqrtf(d1));
            da = __builtin_amdgcn_fdot2(dp, B2(wp[bc][half * 2]), da, false);
            da = __builtin_amdgcn_fdot2(B2(qm0), B2(mp[bc][half * 2]), da, false);
          }
          {
            const int wi = half * 4 + 2;
            h2 e0 = B2(ep[bc][wi])     + B2(qe2);
            h2 e1 = B2(ep[bc][wi + 1]) + B2(qe3);
            float d0 = __builtin_amdgcn_fdot2(e0, e0, EPSF, false);
            float d1 = __builtin_amdgcn_fdot2(e1, e1, EPSF, false);
            h2 dp = cvt_pk(__builtin_amdgcn_sqrtf(d0), __builtin_amdgcn_sqrtf(d1));
            da = __builtin_amdgcn_fdot2(dp, B2(wp[bc][half * 2 + 1]), da, false);
            da = __builtin_amdgcn_fdot2(B2(qm1), B2(mp[bc][half * 2 + 1]), da, false);
          }
          acc[q][bc] = da;
        }
      }
    }
  }

  // ---- epilogue: combine the 4 fq quarters via small LDS ----
  if (fq != 0) {
    #pragma unroll
    for (int q = 0; q < 4; ++q) {
      part[fq - 1][q][0][lane] = acc[q][0];
      part[fq - 1][q][1][lane] = acc[q][1];
    }
  }
  __syncthreads();
  if (fq == 0) {
    const float bias0 = bias[lane];
    const float bias1 = bias[64 + lane];
    #pragma unroll
    for (int q = 0; q < 4; ++q) {
      const size_t row = (size_t)(g * 4 + q) * NBINS;
      float v0 = acc[q][0] + part[0][q][0][lane] + part[1][q][0][lane] +
                 part[2][q][0][lane] + bias0;
      float v1 = acc[q][1] + part[0][q][1][lane] + part[1][q][1][lane] +
                 part[2][q][1][lane] + bias1;
      out[row + lane] = v0;
      out[row + 64 + lane] = v1;
    }
  }
}

extern "C" void kernel_launch(void* const* d_in, const int* in_sizes, int n_in,
                              void* d_out, int out_size, void* d_ws, size_t ws_size,
                              hipStream_t stream) {
  const float* Q      = (const float*)d_in[0];
  const float* probes = (const float*)d_in[1];
  const float* wraw   = (const float*)d_in[2];
  const float* mw     = (const float*)d_in[3];
  const float* bias   = (const float*)d_in[4];
  float* out = (float*)d_out;
  unsigned* ws = (unsigned*)d_ws;  // needs ~6.4 MB; harness provides 256 MB

  prologue13<<<QN_BLOCKS + PACK_BLOCKS, 256, 0, stream>>>(Q, probes, wraw, mw, ws);
  scorer13<<<NQ / 4, 256, 0, stream>>>(ws, bias, out);
}